// Round 5
// baseline (443.684 us; speedup 1.0000x reference)
//
#include <hip/hip_runtime.h>
#include <cstdint>
#include <cstddef>

#define H 128
#define PSTRIDE 512   // packed row: [ch | cc | Ufh | Ah], all bf16 x128

typedef __bf16 v8bf __attribute__((ext_vector_type(8)));
typedef __bf16 v4bf __attribute__((ext_vector_type(4)));
typedef float  v4f  __attribute__((ext_vector_type(4)));

__device__ __forceinline__ float ftanh(float x) {
    return 1.f - 2.f / (1.f + __expf(2.f * x));
}
__device__ __forceinline__ float fsigm(float x) {
    return 1.f / (1.f + __expf(-x));
}

struct GDesc {
    const __bf16* A;    // shared A, stride lda
    int           lda;
    int           nm;   // number of weight mats
    const __bf16* W[5]; // [128,128] bf16 [n][k]
    const float*  bias[5];
    __bf16*       C[5];
    int           ldc[5];
};
struct GBatch { GDesc g[2]; };
struct WPtrs { const float* w[10]; };

// ---------------- prep: wconv (10 mats) + convert x/ch/cc + edge histogram ----------------
__global__ __launch_bounds__(256) void prep_k(WPtrs wp, __bf16* __restrict__ Wb,
                                              const float* __restrict__ x,
                                              const float* __restrict__ chh,
                                              const float* __restrict__ chc,
                                              __bf16* __restrict__ xe,
                                              __bf16* __restrict__ P,
                                              const int* __restrict__ ci,
                                              int* __restrict__ counts,
                                              int MH4, int L) {
    int tid = blockIdx.x * 256 + threadIdx.x;
    if (tid < 40960) {  // 10 * 4096 v4-chunks of weights
        int mat = tid >> 12;
        int off = (tid & 4095) << 2;
        v4f a = *(const v4f*)(wp.w[mat] + off);
        v4bf b;
#pragma unroll
        for (int k = 0; k < 4; ++k) b[k] = (__bf16)a[k];
        *(v4bf*)(Wb + mat * 16384 + off) = b;
        return;
    }
    int i = tid - 40960;
    if (i < MH4) {
        v4f a = ((const v4f*)x)[i];
        v4f b = ((const v4f*)chh)[i];
        v4f c = ((const v4f*)chc)[i];
        v4bf ab, bb, cb;
#pragma unroll
        for (int k = 0; k < 4; ++k) {
            ab[k] = (__bf16)a[k]; bb[k] = (__bf16)b[k]; cb[k] = (__bf16)c[k];
        }
        ((v4bf*)xe)[i] = ab;
        int m = i >> 5;
        int q = (i & 31) << 2;
        __bf16* prow = P + (size_t)m * PSTRIDE + q;
        *(v4bf*)prow = bb;
        *(v4bf*)(prow + H) = cb;
        return;
    }
    int l = i - MH4;
    if (l < L) atomicAdd(&counts[ci[l]], 1);
}

// ---------------- grouped GEMM: shared A-fragments, looped weights, dbuf LDS ----------------
__global__ __launch_bounds__(256) void gemm_group(GBatch gb, int M) {
    const GDesc d = gb.g[blockIdx.y];
    __shared__ __bf16 wlds[2][H][H + 8];

    const int wave = threadIdx.x >> 6;
    const int lane = threadIdx.x & 63;
    const int quad = lane >> 4;
    const int l16  = lane & 15;
    const int r0   = blockIdx.x * 128 + wave * 32;

    // stage mat 0 into buffer 0
#pragma unroll
    for (int i = 0; i < 8; ++i) {
        int c = threadIdx.x + 256 * i;
        int n = c >> 4, k = (c & 15) << 3;
        *(v8bf*)&wlds[0][n][k] = *(const v8bf*)(d.W[0] + n * H + k);
    }

    // A fragments: 2 row-tiles x 4 k-chunks, loaded once
    v8bf afr0[4], afr1[4];
    const __bf16* ar0 = d.A + (size_t)(r0 + l16) * d.lda + quad * 8;
    const __bf16* ar1 = ar0 + (size_t)16 * d.lda;
#pragma unroll
    for (int kc = 0; kc < 4; ++kc) {
        afr0[kc] = *(const v8bf*)(ar0 + kc * 32);
        afr1[kc] = *(const v8bf*)(ar1 + kc * 32);
    }
    __syncthreads();

    for (int mat = 0; mat < d.nm; ++mat) {
        int cur = mat & 1;
        // prefetch next weight into regs (overlaps with MFMA below)
        v8bf pf[8];
        if (mat + 1 < d.nm) {
#pragma unroll
            for (int i = 0; i < 8; ++i) {
                int c = threadIdx.x + 256 * i;
                pf[i] = *(const v8bf*)(d.W[mat + 1] + (c >> 4) * H + ((c & 15) << 3));
            }
        }

        v4f acc0[8], acc1[8];
#pragma unroll
        for (int nt = 0; nt < 8; ++nt) {
            acc0[nt] = (v4f){0.f, 0.f, 0.f, 0.f};
            acc1[nt] = (v4f){0.f, 0.f, 0.f, 0.f};
        }
#pragma unroll
        for (int kc = 0; kc < 4; ++kc) {
#pragma unroll
            for (int nt = 0; nt < 8; ++nt) {
                v8bf b = *(const v8bf*)(&wlds[cur][nt * 16 + l16][kc * 32 + quad * 8]);
                acc0[nt] = __builtin_amdgcn_mfma_f32_16x16x32_bf16(afr0[kc], b, acc0[nt], 0, 0, 0);
                acc1[nt] = __builtin_amdgcn_mfma_f32_16x16x32_bf16(afr1[kc], b, acc1[nt], 0, 0, 0);
            }
        }

        __bf16* Cm = d.C[mat];
        const float* bp = d.bias[mat];
        int ldc = d.ldc[mat];
#pragma unroll
        for (int nt = 0; nt < 8; ++nt) {
            int n = nt * 16 + l16;
            float bia = bp ? bp[n] : 0.f;
#pragma unroll
            for (int r = 0; r < 4; ++r) {
                int m0 = r0 + quad * 4 + r;
                int m1 = m0 + 16;
                if (m0 < M) Cm[(size_t)m0 * ldc + n] = (__bf16)(acc0[nt][r] + bia);
                if (m1 < M) Cm[(size_t)m1 * ldc + n] = (__bf16)(acc1[nt][r] + bia);
            }
        }

        if (mat + 1 < d.nm) {
#pragma unroll
            for (int i = 0; i < 8; ++i) {
                int c = threadIdx.x + 256 * i;
                *(v8bf*)&wlds[cur ^ 1][c >> 4][(c & 15) << 3] = pf[i];
            }
        }
        __syncthreads();
    }
}

// ---------------- scans ----------------
__global__ __launch_bounds__(1024) void scan_local(const int* __restrict__ counts,
                                                   int* __restrict__ excl,
                                                   int* __restrict__ bsums, int M) {
    __shared__ int s[1024];
    int tid = threadIdx.x;
    int idx = blockIdx.x * 1024 + tid;
    int v = (idx < M) ? counts[idx] : 0;
    s[tid] = v;
    __syncthreads();
    for (int off = 1; off < 1024; off <<= 1) {
        int t = (tid >= off) ? s[tid - off] : 0;
        __syncthreads();
        s[tid] += t;
        __syncthreads();
    }
    if (idx < M) excl[idx] = s[tid] - v;
    if (tid == 1023) bsums[blockIdx.x] = s[1023];
}

__global__ __launch_bounds__(1024) void scan_fused(int* __restrict__ rowptr,
                                                   int* __restrict__ cursor,
                                                   const int* __restrict__ bsums,
                                                   const int* __restrict__ counts,
                                                   int M, int nb) {
    __shared__ int s[1024];
    int t = threadIdx.x, b = blockIdx.x;
    int v = (t < nb) ? bsums[t] : 0;
    s[t] = v;
    __syncthreads();
    for (int off = 1; off < 1024; off <<= 1) {
        int tt = (t >= off) ? s[t - off] : 0;
        __syncthreads();
        s[t] += tt;
        __syncthreads();
    }
    int boff = (b == 0) ? 0 : s[b - 1];
    int idx = b * 1024 + t;
    if (idx < M) {
        int val = rowptr[idx] + boff;
        rowptr[idx] = val;
        cursor[idx] = val;
        if (idx == M - 1) rowptr[M] = val + counts[M - 1];
    }
}

// ---------------- scatter: CSR payload = child index ----------------
__global__ __launch_bounds__(256) void scatter_k(const int* __restrict__ ci,
                                                 const int* __restrict__ chi,
                                                 int* __restrict__ cursor,
                                                 int* __restrict__ payload, int L) {
    int l = blockIdx.x * 256 + threadIdx.x;
    if (l < L) {
        int pos = atomicAdd(&cursor[ci[l]], 1);
        payload[pos] = chi[l];
    }
}

// ---------------- fused attention + segment reduce ----------------
// 32 lanes/segment; within a segment, 2 subgroups of 16 lanes each process one
// edge apiece per iteration; each lane covers 8 features (v8bf loads).
__global__ __launch_bounds__(128) void segment_fused(const int* __restrict__ rowptr,
                                                     const int* __restrict__ payload,
                                                     const float* __restrict__ vw,
                                                     const __bf16* __restrict__ Bx,
                                                     const __bf16* __restrict__ Wfx,
                                                     const __bf16* __restrict__ P,
                                                     __bf16* __restrict__ hhat,
                                                     float* __restrict__ sumfc, int M) {
    const int wl   = threadIdx.x & 63;
    const int half = wl & 32;
    const int l32  = wl & 31;
    const int sg   = l32 >> 4;   // edge parity this lane serves
    const int s16  = l32 & 15;
    const int h8   = s16 << 3;   // feature base, 8 feats/lane
    const int m = blockIdx.x * 4 + (threadIdx.x >> 5);
    if (m >= M) return;
    const int start = rowptr[m];
    const int deg   = rowptr[m + 1] - start;

    v8bf bx8 = *(const v8bf*)(Bx + (size_t)m * H + h8);
    v8bf wf8 = *(const v8bf*)(Wfx + (size_t)m * H + h8);
    v4f vva = *(const v4f*)(vw + h8);
    v4f vvb = *(const v4f*)(vw + h8 + 4);
    float bxf[8], wff[8], vvf[8];
#pragma unroll
    for (int k = 0; k < 8; ++k) {
        bxf[k] = (float)bx8[k];
        wff[k] = (float)wf8[k];
        vvf[k] = (k < 4) ? vva[k] : vvb[k - 4];
    }

    int pl0 = (l32 < deg) ? payload[start + l32] : 0;
    int pl1 = (32 + l32 < deg) ? payload[start + 32 + l32] : 0;

    const int jcap  = deg < 64 ? deg : 64;
    const int iters = (jcap + 1) >> 1;

    float e0 = 0.f, e1 = 0.f, denom = 0.f;

    // ---- pass 1: e_j = tanh(Ah[chi]+Bx[m]).v ----
    for (int it = 0; it < iters; ++it) {
        int j = 2 * it + sg;
        int src = half | (j & 31);
        int cj = __shfl((it >= 16) ? pl1 : pl0, src, 64);
        v8bf a8 = *(const v8bf*)(P + (size_t)cj * PSTRIDE + 3 * H + h8);
        float s = 0.f;
#pragma unroll
        for (int k = 0; k < 8; ++k) s += ftanh((float)a8[k] + bxf[k]) * vvf[k];
        s += __shfl_xor(s, 1);
        s += __shfl_xor(s, 2);
        s += __shfl_xor(s, 4);
        s += __shfl_xor(s, 8);
        float ex = (j < jcap) ? __expf(s) : 0.f;
        denom += ex;
        if ((it & 15) == s16) { if (it & 16) e1 = ex; else e0 = ex; }
    }
    // rare tail (deg > 64): denominator only, subgroup-parallel
    for (int j = 64 + sg; j < deg; j += 2) {
        int cj = payload[start + j];
        v8bf a8 = *(const v8bf*)(P + (size_t)cj * PSTRIDE + 3 * H + h8);
        float s = 0.f;
#pragma unroll
        for (int k = 0; k < 8; ++k) s += ftanh((float)a8[k] + bxf[k]) * vvf[k];
        s += __shfl_xor(s, 1);
        s += __shfl_xor(s, 2);
        s += __shfl_xor(s, 4);
        s += __shfl_xor(s, 8);
        denom += __expf(s);
    }
    denom += __shfl_xor(denom, 16);
    float inv = 1.f / (denom + 1e-9f);

    // ---- pass 2: gather [ch|cc|Ufh], attention + forget gates ----
    float acch[8] = {0.f, 0.f, 0.f, 0.f, 0.f, 0.f, 0.f, 0.f};
    float accf[8] = {0.f, 0.f, 0.f, 0.f, 0.f, 0.f, 0.f, 0.f};
    for (int it = 0; it < iters; ++it) {
        int j = 2 * it + sg;
        int src = half | (j & 31);
        int cj = __shfl((it >= 16) ? pl1 : pl0, src, 64);
        int esrc = half | (sg << 4) | (it & 15);
        float exj = __shfl((it & 16) ? e1 : e0, esrc, 64);
        float msk = (j < jcap) ? 1.f : 0.f;
        float a = exj * inv * msk;
        const __bf16* pb = P + (size_t)cj * PSTRIDE + h8;
        v8bf h4 = *(const v8bf*)pb;
        v8bf c4 = *(const v8bf*)(pb + H);
        v8bf u4 = *(const v8bf*)(pb + 2 * H);
#pragma unroll
        for (int k = 0; k < 8; ++k) {
            acch[k] += a * (float)h4[k];
            accf[k] += msk * fsigm(wff[k] + (float)u4[k]) * (float)c4[k];
        }
    }
    // rare tail: recompute e
    for (int j = 64 + sg; j < deg; j += 2) {
        int cj = payload[start + j];
        const __bf16* pb = P + (size_t)cj * PSTRIDE + h8;
        v8bf a8 = *(const v8bf*)(pb + 3 * H);
        float s = 0.f;
#pragma unroll
        for (int k = 0; k < 8; ++k) s += ftanh((float)a8[k] + bxf[k]) * vvf[k];
        s += __shfl_xor(s, 1);
        s += __shfl_xor(s, 2);
        s += __shfl_xor(s, 4);
        s += __shfl_xor(s, 8);
        float a = __expf(s) * inv;
        v8bf h4 = *(const v8bf*)pb;
        v8bf c4 = *(const v8bf*)(pb + H);
        v8bf u4 = *(const v8bf*)(pb + 2 * H);
#pragma unroll
        for (int k = 0; k < 8; ++k) {
            acch[k] += a * (float)h4[k];
            accf[k] += fsigm(wff[k] + (float)u4[k]) * (float)c4[k];
        }
    }

    // combine subgroups
#pragma unroll
    for (int k = 0; k < 8; ++k) {
        acch[k] += __shfl_xor(acch[k], 16);
        accf[k] += __shfl_xor(accf[k], 16);
    }
    if (l32 < 16) {
        v8bf hb;
        v4f sfa, sfb;
#pragma unroll
        for (int k = 0; k < 8; ++k) {
            hb[k] = (__bf16)acch[k];
            if (k < 4) sfa[k] = accf[k]; else sfb[k - 4] = accf[k];
        }
        *(v8bf*)(hhat + (size_t)m * H + h8) = hb;
        *(v4f*)(sumfc + (size_t)m * H + h8) = sfa;
        *(v4f*)(sumfc + (size_t)m * H + h8 + 4) = sfb;
    }
}

// ---------------- epilogue ----------------
__global__ __launch_bounds__(256) void final_k(const __bf16* __restrict__ Xi, const __bf16* __restrict__ Hi,
                                               const __bf16* __restrict__ Xc, const __bf16* __restrict__ Hc,
                                               const __bf16* __restrict__ Xo, const __bf16* __restrict__ Ho,
                                               const float* __restrict__ sumfc,
                                               float* __restrict__ out, int MH4, int MH) {
    int i = blockIdx.x * 256 + threadIdx.x;
    if (i >= MH4) return;
    v4bf xi = ((const v4bf*)Xi)[i], hi = ((const v4bf*)Hi)[i];
    v4bf xc = ((const v4bf*)Xc)[i], hc = ((const v4bf*)Hc)[i];
    v4bf xo = ((const v4bf*)Xo)[i], ho = ((const v4bf*)Ho)[i];
    v4f sf = ((const v4f*)sumfc)[i];
    v4f hout, cout;
#pragma unroll
    for (int k = 0; k < 4; ++k) {
        float ig = fsigm((float)xi[k] + (float)hi[k]);
        float ct = ftanh((float)xc[k] + (float)hc[k]);
        float og = fsigm((float)xo[k] + (float)ho[k]);
        float c = ig * ct + sf[k];
        cout[k] = c;
        hout[k] = og * ftanh(c);
    }
    ((v4f*)out)[i] = hout;
    ((v4f*)(out + MH))[i] = cout;
}

extern "C" void kernel_launch(void* const* d_in, const int* in_sizes, int n_in,
                              void* d_out, int out_size, void* d_ws, size_t ws_size,
                              hipStream_t stream) {
    const float* x_emb   = (const float*)d_in[0];
    const float* child_h = (const float*)d_in[1];
    const float* child_c = (const float*)d_in[2];
    const int*   ci      = (const int*)d_in[3];
    const int*   chi     = (const int*)d_in[4];
    const float* Wi_b = (const float*)d_in[15];
    const float* Wf_b = (const float*)d_in[16];
    const float* Wo_b = (const float*)d_in[17];
    const float* Wc_b = (const float*)d_in[18];
    const float* Wa_b = (const float*)d_in[19];
    const float* vw   = (const float*)d_in[20];

    const int M    = in_sizes[0] / H;
    const int L    = in_sizes[3];
    const int Mpad = (M + 127) & ~127;
    const int MH   = M * H;
    const int MH4  = MH / 4;

    char* p = (char*)d_ws;
    auto alloc = [&](size_t bytes) {
        char* r = p;
        p += (bytes + 255) & ~(size_t)255;
        return (void*)r;
    };
    size_t bfbytes = (size_t)Mpad * H * sizeof(__bf16);
    __bf16* xe16   = (__bf16*)alloc(bfbytes);
    __bf16* P      = (__bf16*)alloc((size_t)Mpad * PSTRIDE * sizeof(__bf16));
    __bf16* hhat16 = (__bf16*)alloc(bfbytes);
    __bf16* Bx16   = (__bf16*)alloc(bfbytes);
    __bf16* Wfx16  = (__bf16*)alloc(bfbytes);
    __bf16* Xi16   = (__bf16*)alloc(bfbytes);
    __bf16* Xc16   = (__bf16*)alloc(bfbytes);
    __bf16* Xo16   = (__bf16*)alloc(bfbytes);
    __bf16* Wb     = (__bf16*)alloc(10 * 16384 * sizeof(__bf16));
    float* sumfc   = (float*)alloc((size_t)MH * 4);
    int*   payload = (int*)alloc((size_t)L * 4);
    int*   counts  = (int*)alloc((size_t)M * 4);
    int*   rowptr  = (int*)alloc((size_t)(M + 1) * 4);
    int*   cursor  = (int*)alloc((size_t)M * 4);
    int*   bsums   = (int*)alloc(1024 * 4);
    // reuse after segment_fused: Bx -> Hi, Wfx -> Hc, P -> Ho (flat)
    __bf16* Hi16 = Bx16;
    __bf16* Hc16 = Wfx16;
    __bf16* Ho16 = P;

    hipMemsetAsync(counts, 0, (size_t)M * 4, stream);

    WPtrs wp;
    for (int k = 0; k < 10; ++k) wp.w[k] = (const float*)d_in[5 + k];
    int prep_items = 40960 + MH4 + L;
    prep_k<<<(prep_items + 255) / 256, 256, 0, stream>>>(wp, Wb, x_emb, child_h, child_c,
                                                         xe16, P, ci, counts, MH4, L);

    const __bf16* Wi = Wb + 0 * 16384;
    const __bf16* Ui = Wb + 1 * 16384;
    const __bf16* Wf = Wb + 2 * 16384;
    const __bf16* Uf = Wb + 3 * 16384;
    const __bf16* Wo = Wb + 4 * 16384;
    const __bf16* Uo = Wb + 5 * 16384;
    const __bf16* Wc = Wb + 6 * 16384;
    const __bf16* Uc = Wb + 7 * 16384;
    const __bf16* Wa = Wb + 8 * 16384;
    const __bf16* Ua = Wb + 9 * 16384;

    // pass A: group0 shares A=xe16 (5 mats), group1 shares A=P ch-section (2 mats)
    GBatch ga{};
    ga.g[0].A = xe16; ga.g[0].lda = H; ga.g[0].nm = 5;
    ga.g[0].W[0] = Ua; ga.g[0].bias[0] = nullptr; ga.g[0].C[0] = Bx16;  ga.g[0].ldc[0] = H;
    ga.g[0].W[1] = Wf; ga.g[0].bias[1] = Wf_b;    ga.g[0].C[1] = Wfx16; ga.g[0].ldc[1] = H;
    ga.g[0].W[2] = Wi; ga.g[0].bias[2] = Wi_b;    ga.g[0].C[2] = Xi16;  ga.g[0].ldc[2] = H;
    ga.g[0].W[3] = Wc; ga.g[0].bias[3] = Wc_b;    ga.g[0].C[3] = Xc16;  ga.g[0].ldc[3] = H;
    ga.g[0].W[4] = Wo; ga.g[0].bias[4] = Wo_b;    ga.g[0].C[4] = Xo16;  ga.g[0].ldc[4] = H;
    ga.g[1].A = P; ga.g[1].lda = PSTRIDE; ga.g[1].nm = 2;
    ga.g[1].W[0] = Wa; ga.g[1].bias[0] = Wa_b;    ga.g[1].C[0] = P + 3 * H; ga.g[1].ldc[0] = PSTRIDE;
    ga.g[1].W[1] = Uf; ga.g[1].bias[1] = nullptr; ga.g[1].C[1] = P + 2 * H; ga.g[1].ldc[1] = PSTRIDE;
    dim3 gA(Mpad / 128, 2);
    gemm_group<<<gA, 256, 0, stream>>>(ga, M);

    int nb = (M + 1023) / 1024;
    scan_local<<<nb, 1024, 0, stream>>>(counts, rowptr, bsums, M);
    scan_fused<<<nb, 1024, 0, stream>>>(rowptr, cursor, bsums, counts, M, nb);

    scatter_k<<<(L + 255) / 256, 256, 0, stream>>>(ci, chi, cursor, payload, L);

    segment_fused<<<(M + 3) / 4, 128, 0, stream>>>(rowptr, payload, vw, Bx16, Wfx16, P,
                                                   hhat16, sumfc, M);

    // pass B: all 3 mats share A=hhat
    GBatch gbb{};
    gbb.g[0].A = hhat16; gbb.g[0].lda = H; gbb.g[0].nm = 3;
    gbb.g[0].W[0] = Ui; gbb.g[0].bias[0] = nullptr; gbb.g[0].C[0] = Hi16; gbb.g[0].ldc[0] = H;
    gbb.g[0].W[1] = Uc; gbb.g[0].bias[1] = nullptr; gbb.g[0].C[1] = Hc16; gbb.g[0].ldc[1] = H;
    gbb.g[0].W[2] = Uo; gbb.g[0].bias[2] = nullptr; gbb.g[0].C[2] = Ho16; gbb.g[0].ldc[2] = H;
    dim3 gB(Mpad / 128, 1);
    gemm_group<<<gB, 256, 0, stream>>>(gbb, M);

    final_k<<<(MH4 + 255) / 256, 256, 0, stream>>>(Xi16, Hi16, Xc16, Hc16, Xo16, Ho16, sumfc,
                                                   (float*)d_out, MH4, MH);
}

// Round 6
// 399.770 us; speedup vs baseline: 1.1098x; 1.1098x over previous
//
#include <hip/hip_runtime.h>
#include <cstdint>
#include <cstddef>

#define H 128
#define PSTRIDE 512   // packed row: [ch | cc | Ufh | Ah], all bf16 x128

typedef __bf16 v8bf __attribute__((ext_vector_type(8)));
typedef __bf16 v4bf __attribute__((ext_vector_type(4)));
typedef float  v4f  __attribute__((ext_vector_type(4)));

__device__ __forceinline__ float ftanh(float x) {
    return 1.f - 2.f / (1.f + __expf(2.f * x));
}
__device__ __forceinline__ float fsigm(float x) {
    return 1.f / (1.f + __expf(-x));
}

struct MatDesc {
    const __bf16* A;    // bf16 A, stride lda
    int           lda;
    const __bf16* Wb;   // [128,128] bf16 [n][k]
    const float*  bias; // [128] or nullptr
    __bf16*       C;    // bf16 out, stride ldc
    int           ldc;
};
struct MatBatch { MatDesc m[7]; };
struct WPtrs { const float* w[10]; };

// ---------------- prep: wconv (10 mats) + convert x/ch/cc + edge histogram ----------------
__global__ __launch_bounds__(256) void prep_k(WPtrs wp, __bf16* __restrict__ Wb,
                                              const float* __restrict__ x,
                                              const float* __restrict__ chh,
                                              const float* __restrict__ chc,
                                              __bf16* __restrict__ xe,
                                              __bf16* __restrict__ P,
                                              const int* __restrict__ ci,
                                              int* __restrict__ counts,
                                              int MH4, int L) {
    int tid = blockIdx.x * 256 + threadIdx.x;
    if (tid < 40960) {  // 10 * 4096 v4-chunks of weights
        int mat = tid >> 12;
        int off = (tid & 4095) << 2;
        v4f a = *(const v4f*)(wp.w[mat] + off);
        v4bf b;
#pragma unroll
        for (int k = 0; k < 4; ++k) b[k] = (__bf16)a[k];
        *(v4bf*)(Wb + mat * 16384 + off) = b;
        return;
    }
    int i = tid - 40960;
    if (i < MH4) {
        v4f a = ((const v4f*)x)[i];
        v4f b = ((const v4f*)chh)[i];
        v4f c = ((const v4f*)chc)[i];
        v4bf ab, bb, cb;
#pragma unroll
        for (int k = 0; k < 4; ++k) {
            ab[k] = (__bf16)a[k]; bb[k] = (__bf16)b[k]; cb[k] = (__bf16)c[k];
        }
        ((v4bf*)xe)[i] = ab;
        int m = i >> 5;
        int q = (i & 31) << 2;
        __bf16* prow = P + (size_t)m * PSTRIDE + q;
        *(v4bf*)prow = bb;
        *(v4bf*)(prow + H) = cb;
        return;
    }
    int l = i - MH4;
    if (l < L) atomicAdd(&counts[ci[l]], 1);
}

// ---------------- batched GEMM: 128 rows/block, 2 row-tiles/wave share B ds_reads ----------------
__global__ __launch_bounds__(256) void gemm_batch(MatBatch batch, int M) {
    const MatDesc d = batch.m[blockIdx.y];
    __shared__ __bf16 wlds[H][H + 8];

    for (int t = threadIdx.x; t < 2048; t += 256) {
        int n = t >> 4;
        int k = (t & 15) << 3;
        *(v8bf*)&wlds[n][k] = *(const v8bf*)(d.Wb + n * H + k);
    }
    __syncthreads();

    const int wave = threadIdx.x >> 6;
    const int lane = threadIdx.x & 63;
    const int quad = lane >> 4;
    const int l16  = lane & 15;
    const int r0   = blockIdx.x * 128 + wave * 32;

    v4f acc0[8], acc1[8];
#pragma unroll
    for (int nt = 0; nt < 8; ++nt) {
        acc0[nt] = (v4f){0.f, 0.f, 0.f, 0.f};
        acc1[nt] = (v4f){0.f, 0.f, 0.f, 0.f};
    }

    const __bf16* ar0 = d.A + (size_t)(r0 + l16) * d.lda + quad * 8;
    const __bf16* ar1 = d.A + (size_t)(r0 + 16 + l16) * d.lda + quad * 8;
#pragma unroll
    for (int k0 = 0; k0 < H; k0 += 32) {
        v8bf a0 = *(const v8bf*)(ar0 + k0);
        v8bf a1 = *(const v8bf*)(ar1 + k0);
#pragma unroll
        for (int nt = 0; nt < 8; ++nt) {
            v8bf b = *(const v8bf*)(&wlds[nt * 16 + l16][k0 + quad * 8]);
            acc0[nt] = __builtin_amdgcn_mfma_f32_16x16x32_bf16(a0, b, acc0[nt], 0, 0, 0);
            acc1[nt] = __builtin_amdgcn_mfma_f32_16x16x32_bf16(a1, b, acc1[nt], 0, 0, 0);
        }
    }

#pragma unroll
    for (int nt = 0; nt < 8; ++nt) {
        int n = nt * 16 + l16;
        float bia = d.bias ? d.bias[n] : 0.f;
#pragma unroll
        for (int r = 0; r < 4; ++r) {
            int m0 = r0 + quad * 4 + r;
            int m1 = m0 + 16;
            if (m0 < M) d.C[(size_t)m0 * d.ldc + n] = (__bf16)(acc0[nt][r] + bia);
            if (m1 < M) d.C[(size_t)m1 * d.ldc + n] = (__bf16)(acc1[nt][r] + bia);
        }
    }
}

// ---------------- scans ----------------
__global__ __launch_bounds__(1024) void scan_local(const int* __restrict__ counts,
                                                   int* __restrict__ excl,
                                                   int* __restrict__ bsums, int M) {
    __shared__ int s[1024];
    int tid = threadIdx.x;
    int idx = blockIdx.x * 1024 + tid;
    int v = (idx < M) ? counts[idx] : 0;
    s[tid] = v;
    __syncthreads();
    for (int off = 1; off < 1024; off <<= 1) {
        int t = (tid >= off) ? s[tid - off] : 0;
        __syncthreads();
        s[tid] += t;
        __syncthreads();
    }
    if (idx < M) excl[idx] = s[tid] - v;
    if (tid == 1023) bsums[blockIdx.x] = s[1023];
}

__global__ __launch_bounds__(1024) void scan_fused(int* __restrict__ rowptr,
                                                   int* __restrict__ cursor,
                                                   const int* __restrict__ bsums,
                                                   const int* __restrict__ counts,
                                                   int M, int nb) {
    __shared__ int s[1024];
    int t = threadIdx.x, b = blockIdx.x;
    int v = (t < nb) ? bsums[t] : 0;
    s[t] = v;
    __syncthreads();
    for (int off = 1; off < 1024; off <<= 1) {
        int tt = (t >= off) ? s[t - off] : 0;
        __syncthreads();
        s[t] += tt;
        __syncthreads();
    }
    int boff = (b == 0) ? 0 : s[b - 1];
    int idx = b * 1024 + t;
    if (idx < M) {
        int val = rowptr[idx] + boff;
        rowptr[idx] = val;
        cursor[idx] = val;
        if (idx == M - 1) rowptr[M] = val + counts[M - 1];
    }
}

// ---------------- scatter: CSR payload = child index ----------------
__global__ __launch_bounds__(256) void scatter_k(const int* __restrict__ ci,
                                                 const int* __restrict__ chi,
                                                 int* __restrict__ cursor,
                                                 int* __restrict__ payload, int L) {
    int l = blockIdx.x * 256 + threadIdx.x;
    if (l < L) {
        int pos = atomicAdd(&cursor[ci[l]], 1);
        payload[pos] = chi[l];
    }
}

// ---------------- fused attention + segment reduce, SINGLE PASS ----------------
// 32 lanes/segment, 4 feats/lane. Accumulate unnormalized ex*h and ex; scale at end.
// Butterfly reduce leaves s in all lanes -> ex available everywhere, no broadcast.
__global__ __launch_bounds__(128) void segment_fused(const int* __restrict__ rowptr,
                                                     const int* __restrict__ payload,
                                                     const float* __restrict__ vw,
                                                     const __bf16* __restrict__ Bx,
                                                     const __bf16* __restrict__ Wfx,
                                                     const __bf16* __restrict__ P,
                                                     __bf16* __restrict__ hhat,
                                                     float* __restrict__ sumfc, int M) {
    const int wl   = threadIdx.x & 63;
    const int half = wl & 32;
    const int l32  = wl & 31;
    const int m = blockIdx.x * 4 + (threadIdx.x >> 5);
    if (m >= M) return;
    const int start = rowptr[m];
    const int deg   = rowptr[m + 1] - start;
    const int h = l32 << 2;

    v4bf bx4 = *(const v4bf*)(Bx + (size_t)m * H + h);
    v4bf wf4 = *(const v4bf*)(Wfx + (size_t)m * H + h);
    v4f  vv  = *(const v4f*)(vw + h);
    float bxf[4], wff[4];
#pragma unroll
    for (int k = 0; k < 4; ++k) { bxf[k] = (float)bx4[k]; wff[k] = (float)wf4[k]; }

    // batch payload loads (1 per lane per 32 edges)
    int pl0 = (l32 < deg) ? payload[start + l32] : 0;
    int pl1 = (32 + l32 < deg) ? payload[start + 32 + l32] : 0;

    float denom = 0.f;
    float acch[4] = {0.f, 0.f, 0.f, 0.f};
    float accf[4] = {0.f, 0.f, 0.f, 0.f};

    const int jcap = deg < 64 ? deg : 64;
    for (int j = 0; j < jcap; ++j) {
        int cj = __shfl((j & 32) ? pl1 : pl0, half | (j & 31), 64);
        const __bf16* pb = P + (size_t)cj * PSTRIDE + h;
        v4bf h4 = *(const v4bf*)pb;
        v4bf c4 = *(const v4bf*)(pb + H);
        v4bf u4 = *(const v4bf*)(pb + 2 * H);
        v4bf a4 = *(const v4bf*)(pb + 3 * H);
        float s = 0.f;
#pragma unroll
        for (int k = 0; k < 4; ++k) s += ftanh((float)a4[k] + bxf[k]) * vv[k];
        s += __shfl_xor(s, 1);
        s += __shfl_xor(s, 2);
        s += __shfl_xor(s, 4);
        s += __shfl_xor(s, 8);
        s += __shfl_xor(s, 16);
        float ex = __expf(s);
        denom += ex;
#pragma unroll
        for (int k = 0; k < 4; ++k) {
            acch[k] += ex * (float)h4[k];
            accf[k] += fsigm(wff[k] + (float)u4[k]) * (float)c4[k];
        }
    }
    // rare tail (deg > 64)
    for (int j = 64; j < deg; ++j) {
        int cj = payload[start + j];
        const __bf16* pb = P + (size_t)cj * PSTRIDE + h;
        v4bf h4 = *(const v4bf*)pb;
        v4bf c4 = *(const v4bf*)(pb + H);
        v4bf u4 = *(const v4bf*)(pb + 2 * H);
        v4bf a4 = *(const v4bf*)(pb + 3 * H);
        float s = 0.f;
#pragma unroll
        for (int k = 0; k < 4; ++k) s += ftanh((float)a4[k] + bxf[k]) * vv[k];
        s += __shfl_xor(s, 1);
        s += __shfl_xor(s, 2);
        s += __shfl_xor(s, 4);
        s += __shfl_xor(s, 8);
        s += __shfl_xor(s, 16);
        float ex = __expf(s);
        denom += ex;
#pragma unroll
        for (int k = 0; k < 4; ++k) {
            acch[k] += ex * (float)h4[k];
            accf[k] += fsigm(wff[k] + (float)u4[k]) * (float)c4[k];
        }
    }

    float inv = 1.f / (denom + 1e-9f);
    v4bf hb;
    v4f sf;
#pragma unroll
    for (int k = 0; k < 4; ++k) { hb[k] = (__bf16)(acch[k] * inv); sf[k] = accf[k]; }
    *(v4bf*)(hhat + (size_t)m * H + h) = hb;
    *(v4f*)(sumfc + (size_t)m * H + h) = sf;
}

// ---------------- epilogue ----------------
__global__ __launch_bounds__(256) void final_k(const __bf16* __restrict__ Xi, const __bf16* __restrict__ Hi,
                                               const __bf16* __restrict__ Xc, const __bf16* __restrict__ Hc,
                                               const __bf16* __restrict__ Xo, const __bf16* __restrict__ Ho,
                                               const float* __restrict__ sumfc,
                                               float* __restrict__ out, int MH4, int MH) {
    int i = blockIdx.x * 256 + threadIdx.x;
    if (i >= MH4) return;
    v4bf xi = ((const v4bf*)Xi)[i], hi = ((const v4bf*)Hi)[i];
    v4bf xc = ((const v4bf*)Xc)[i], hc = ((const v4bf*)Hc)[i];
    v4bf xo = ((const v4bf*)Xo)[i], ho = ((const v4bf*)Ho)[i];
    v4f sf = ((const v4f*)sumfc)[i];
    v4f hout, cout;
#pragma unroll
    for (int k = 0; k < 4; ++k) {
        float ig = fsigm((float)xi[k] + (float)hi[k]);
        float ct = ftanh((float)xc[k] + (float)hc[k]);
        float og = fsigm((float)xo[k] + (float)ho[k]);
        float c = ig * ct + sf[k];
        cout[k] = c;
        hout[k] = og * ftanh(c);
    }
    ((v4f*)out)[i] = hout;
    ((v4f*)(out + MH))[i] = cout;
}

extern "C" void kernel_launch(void* const* d_in, const int* in_sizes, int n_in,
                              void* d_out, int out_size, void* d_ws, size_t ws_size,
                              hipStream_t stream) {
    const float* x_emb   = (const float*)d_in[0];
    const float* child_h = (const float*)d_in[1];
    const float* child_c = (const float*)d_in[2];
    const int*   ci      = (const int*)d_in[3];
    const int*   chi     = (const int*)d_in[4];
    const float* Wi_b = (const float*)d_in[15];
    const float* Wf_b = (const float*)d_in[16];
    const float* Wo_b = (const float*)d_in[17];
    const float* Wc_b = (const float*)d_in[18];
    const float* Wa_b = (const float*)d_in[19];
    const float* vw   = (const float*)d_in[20];

    const int M    = in_sizes[0] / H;
    const int L    = in_sizes[3];
    const int Mpad = (M + 127) & ~127;
    const int MH   = M * H;
    const int MH4  = MH / 4;

    char* p = (char*)d_ws;
    auto alloc = [&](size_t bytes) {
        char* r = p;
        p += (bytes + 255) & ~(size_t)255;
        return (void*)r;
    };
    size_t bfbytes = (size_t)Mpad * H * sizeof(__bf16);
    __bf16* xe16   = (__bf16*)alloc(bfbytes);
    __bf16* P      = (__bf16*)alloc((size_t)Mpad * PSTRIDE * sizeof(__bf16));
    __bf16* hhat16 = (__bf16*)alloc(bfbytes);
    __bf16* Bx16   = (__bf16*)alloc(bfbytes);
    __bf16* Wfx16  = (__bf16*)alloc(bfbytes);
    __bf16* Xi16   = (__bf16*)alloc(bfbytes);
    __bf16* Xc16   = (__bf16*)alloc(bfbytes);
    __bf16* Xo16   = (__bf16*)alloc(bfbytes);
    __bf16* Wb     = (__bf16*)alloc(10 * 16384 * sizeof(__bf16));
    float* sumfc   = (float*)alloc((size_t)MH * 4);
    int*   payload = (int*)alloc((size_t)L * 4);
    int*   counts  = (int*)alloc((size_t)M * 4);
    int*   rowptr  = (int*)alloc((size_t)(M + 1) * 4);
    int*   cursor  = (int*)alloc((size_t)M * 4);
    int*   bsums   = (int*)alloc(1024 * 4);
    // reuse after segment_fused: Bx -> Hi, Wfx -> Hc, P -> Ho (flat)
    __bf16* Hi16 = Bx16;
    __bf16* Hc16 = Wfx16;
    __bf16* Ho16 = P;

    hipMemsetAsync(counts, 0, (size_t)M * 4, stream);

    WPtrs wp;
    for (int k = 0; k < 10; ++k) wp.w[k] = (const float*)d_in[5 + k];
    int prep_items = 40960 + MH4 + L;
    prep_k<<<(prep_items + 255) / 256, 256, 0, stream>>>(wp, Wb, x_emb, child_h, child_c,
                                                         xe16, P, ci, counts, MH4, L);

    const __bf16* Wi = Wb + 0 * 16384;
    const __bf16* Ui = Wb + 1 * 16384;
    const __bf16* Wf = Wb + 2 * 16384;
    const __bf16* Uf = Wb + 3 * 16384;
    const __bf16* Wo = Wb + 4 * 16384;
    const __bf16* Uo = Wb + 5 * 16384;
    const __bf16* Wc = Wb + 6 * 16384;
    const __bf16* Uc = Wb + 7 * 16384;
    const __bf16* Wa = Wb + 8 * 16384;
    const __bf16* Ua = Wb + 9 * 16384;

    MatBatch ba{};
    ba.m[0] = MatDesc{P,    PSTRIDE, Wa, Wa_b,    P + 3 * H, PSTRIDE}; // Ah -> P sec3
    ba.m[1] = MatDesc{xe16, H,       Ua, nullptr, Bx16,      H};       // Bx
    ba.m[2] = MatDesc{xe16, H,       Wf, Wf_b,    Wfx16,     H};       // Wfx
    ba.m[3] = MatDesc{P,    PSTRIDE, Uf, nullptr, P + 2 * H, PSTRIDE}; // Ufh -> P sec2
    ba.m[4] = MatDesc{xe16, H,       Wi, Wi_b,    Xi16,      H};
    ba.m[5] = MatDesc{xe16, H,       Wc, Wc_b,    Xc16,      H};
    ba.m[6] = MatDesc{xe16, H,       Wo, Wo_b,    Xo16,      H};
    dim3 gA(Mpad / 128, 7);
    gemm_batch<<<gA, 256, 0, stream>>>(ba, M);

    int nb = (M + 1023) / 1024;
    scan_local<<<nb, 1024, 0, stream>>>(counts, rowptr, bsums, M);
    scan_fused<<<nb, 1024, 0, stream>>>(rowptr, cursor, bsums, counts, M, nb);

    scatter_k<<<(L + 255) / 256, 256, 0, stream>>>(ci, chi, cursor, payload, L);

    segment_fused<<<(M + 3) / 4, 128, 0, stream>>>(rowptr, payload, vw, Bx16, Wfx16, P,
                                                   hhat16, sumfc, M);

    MatBatch bb{};
    bb.m[0] = MatDesc{hhat16, H, Ui, nullptr, Hi16, H};
    bb.m[1] = MatDesc{hhat16, H, Uc, nullptr, Hc16, H};
    bb.m[2] = MatDesc{hhat16, H, Uo, nullptr, Ho16, H};
    dim3 gB(Mpad / 128, 3);
    gemm_batch<<<gB, 256, 0, stream>>>(bb, M);

    final_k<<<(MH4 + 255) / 256, 256, 0, stream>>>(Xi16, Hi16, Xc16, Hc16, Xo16, Ho16, sumfc,
                                                   (float*)d_out, MH4, MH);
}